// Round 12
// baseline (25410.663 us; speedup 1.0000x reference)
//
#include <hip/hip_runtime.h>

typedef __attribute__((ext_vector_type(4))) int   i32x4;
typedef __attribute__((ext_vector_type(8))) short s16x8;
typedef __attribute__((ext_vector_type(4))) float f32x4;

__device__ __forceinline__ unsigned short f2bf(float f) {
  unsigned u = __float_as_uint(f);
  unsigned r = u + 0x7FFFu + ((u >> 16) & 1u);
  return (unsigned short)(r >> 16);
}
__device__ __forceinline__ unsigned pack2bf(float lo, float hi) {
  return (unsigned)f2bf(lo) | ((unsigned)f2bf(hi) << 16);
}
__device__ __forceinline__ float bflo(unsigned u){ return __uint_as_float(u << 16); }
__device__ __forceinline__ float bfhi(unsigned u){ return __uint_as_float(u & 0xFFFF0000u); }

__device__ __forceinline__ float sigm(float x){ return 1.0f / (1.0f + __expf(-x)); }
__device__ __forceinline__ float tanh_(float x){
  float ax = fabsf(x);
  float e  = __expf(-2.0f * ax);
  float t  = (1.0f - e) / (1.0f + e);
  return copysignf(t, x);
}

__device__ __forceinline__ unsigned long long aload(const unsigned long long* p) {
  return __hip_atomic_load(p, __ATOMIC_RELAXED, __HIP_MEMORY_SCOPE_AGENT);
}
__device__ __forceinline__ void astore32(unsigned* p, unsigned v) {
  __hip_atomic_store(p, v, __ATOMIC_RELAXED, __HIP_MEMORY_SCOPE_AGENT);
}

// 16-flag wait, packed layout: lanes watch consecutive u32 (one line).
__device__ __forceinline__ void waitflags(const unsigned* F, int base, unsigned need, int lane) {
  const unsigned* p = F + base + (lane & 15);
  unsigned v = __hip_atomic_load(p, __ATOMIC_RELAXED, __HIP_MEMORY_SCOPE_AGENT);
  while (!__all((int)(v >= need))) {
    __builtin_amdgcn_s_sleep(1);
    v = __hip_atomic_load(p, __ATOMIC_RELAXED, __HIP_MEMORY_SCOPE_AGENT);
  }
}

// ---------------- input projection ----------------
__global__ __launch_bounds__(256) void k_inproj(const float* __restrict__ x,
                                                const float* __restrict__ w,
                                                const float* __restrict__ bb,
                                                float* __restrict__ XP) {
  int idx = blockIdx.x * 256 + threadIdx.x;
  int b = idx >> 9, j = idx & 511;
  float acc = bb[j];
#pragma unroll
  for (int k = 0; k < 12; ++k) acc += x[b * 12 + k] * w[j * 12 + k];
  XP[idx] = acc;
}

// ---------------- layer-0 input gates (constant over t) ----------------
__global__ __launch_bounds__(256) void k_xg0(const float* __restrict__ XP,
                                             const float* __restrict__ Wih,
                                             const float* __restrict__ bih,
                                             float* __restrict__ XG0) {
  int idx = blockIdx.x * 256 + threadIdx.x;
  int b = idx & 31;
  int r = idx >> 5;
  const float* wr = Wih + (size_t)r * 512;
  const float* xr = XP + b * 512;
  float acc = bih[r];
  for (int k = 0; k < 512; k += 4) {
    const f32x4 w4 = *(const f32x4*)(wr + k);
    const f32x4 x4 = *(const f32x4*)(xr + k);
    acc += w4[0]*x4[0] + w4[1]*x4[1] + w4[2]*x4[2] + w4[3]*x4[3];
  }
  XG0[b * 2048 + r] = acc;
}

// ---------------- 6-layer pipelined scan: 16 WGs x 512 thr per layer ----------------
// 96 WGs: layer = wgid>>4, w = wgid&15 owns 32 h-cols [32w,32w+32). 8 waves:
// gate = wv>>1, col-half = wv&1 (16 cols per wave; B-frag VGPR same as R11).
// Halved fan-in: 16 flags/layer (one line per poll), straggler pool 16,
// h-load queue 8 u64/thread. Sync semantics identical to R11 (unconditional
// publishes; waits own<=2048, producer<=2049, Prog<=2043 — all terminate).
__global__ __launch_bounds__(512, 1) void k_pipe(
    const float* __restrict__ Wih, const float* __restrict__ Whh,
    const float* __restrict__ bih, const float* __restrict__ bhh,
    const float* __restrict__ lnS, const float* __restrict__ lnB,
    const float* __restrict__ XG0, const float* __restrict__ XP,
    unsigned long long* __restrict__ Hst,    // [6][2][4096] u64 (2 bf16-pairs)
    unsigned long long* __restrict__ Roll,   // [5][4][4096] u64
    unsigned* __restrict__ RB,               // [32][2048][256] layer-5 rows
    unsigned* __restrict__ Flg,              // [6][16] packed u32
    unsigned* __restrict__ Prog)             // [6][16] packed u32
{
  __shared__ char smem[83968];
  const int tid   = threadIdx.x;
  const int wgid  = blockIdx.x;
  const int layer = wgid >> 4;
  const int w     = wgid & 15;

  char* xarea = smem;            // 32 KB: LN'd input row (l>=1) / L0 statics
  char* harea = smem + 32768;    // 32 KB: staged h
  float* gacc = (float*)(smem + 65536);   // [4][32][36] f32, disjoint (18 KB)
  const int lane = tid & 63;
  const int wv   = tid >> 6;     // 0..7
  const int gt   = wv >> 1;      // gate
  const int ch   = wv & 1;       // col-half within WG
  const int j0   = w << 5;       // 32 cols per WG

  unsigned long long* HstL = Hst + layer * 8192;

  // ---- B-fragment preload (per wave: 16 cols of gate gt) ----
  s16x8 bfih[16], bfhh[16];
  {
    const int rcol = lane & 15;
    const int kg   = lane >> 4;
    const size_t rowbase = ((size_t)layer * 2048 + (size_t)(gt * 512 + j0 + ch * 16 + rcol)) * 512;
    const float* ihr = Wih + rowbase;
    const float* hhr = Whh + rowbase;
#pragma unroll
    for (int kk = 0; kk < 16; ++kk) {
      const int k0 = kg * 8 + kk * 32;
      s16x8 v2;
#pragma unroll
      for (int j = 0; j < 8; ++j) v2[j] = (short)f2bf(hhr[k0 + j]);
      bfhh[kk] = v2;
      if (layer > 0) {
        s16x8 v1;
#pragma unroll
        for (int j = 0; j < 8; ++j) v1[j] = (short)f2bf(ihr[k0 + j]);
        bfih[kk] = v1;
      }
    }
  }

  const int ub = tid >> 4;            // batch row (cell update), 0..31
  const int jp = tid & 15;            // col-pair within WG, 0..15
  const int kpglob = (j0 >> 1) + jp;  // global u32 pair index 0..255

  float bs[4][2];
#pragma unroll
  for (int g = 0; g < 4; ++g)
#pragma unroll
    for (int c = 0; c < 2; ++c) {
      const size_t r = (size_t)layer * 2048 + g * 512 + j0 + 2 * jp + c;
      float vv = bhh[r];
      if (layer > 0) vv += bih[r];    // L0: b_ih folded into XG0
      bs[g][c] = vv;
    }

  const float* lnSl = lnS + (layer - 1) * 512;   // valid only layer>0
  const float* lnBl = lnB + (layer - 1) * 512;

  if (layer == 0) {
    float* xg0s = (float*)smem;            // [4][32][32] f32 (16 KB)
    float* xps  = (float*)(smem + 16384);  // [32][32] f32 (4 KB)
    for (int i = tid; i < 4096; i += 512) {
      int g = i >> 10, b = (i >> 5) & 31, jl = i & 31;
      xg0s[i] = XG0[b * 2048 + g * 512 + j0 + jl];
    }
    for (int i = tid; i < 1024; i += 512) {
      int b = i >> 5, jl = i & 31;
      xps[i] = XP[b * 512 + j0 + jl];
    }
  }

  // ---- h0 = 0 into slot 0 (own 512-u32 slice); publish flag = 1 ----
  astore32((unsigned*)HstL + (ub << 8) + kpglob, 0u);
  __syncthreads();   // drains vmcnt: zero-stores visible before flag
  if (tid == 0)
    __hip_atomic_store(Flg + layer * 16 + w, 1u, __ATOMIC_RELEASE, __HIP_MEMORY_SCOPE_AGENT);

  float xinc0 = 0.f, xinc1 = 0.f;
  if (layer == 0) {
    const float* xps = (const float*)(smem + 16384);
    xinc0 = xps[ub * 32 + 2 * jp];
    xinc1 = xps[ub * 32 + 2 * jp + 1];
  }

  const int rr  = tid >> 4;   // LN row 0..31
  const int kk8 = tid & 15;   // LN u64 lane within row 0..15 (8 u64 each)

  // ---- pre-loop blocking LN-stage of row 0 (layer>0): producer flag >= 2 ----
  if (layer > 0) {
    waitflags(Flg, (layer - 1) * 16, 2u, lane);
    const unsigned long long* RollC = Roll + (layer - 1) * 16384;   // slot 0
    unsigned long long xr[8];
#pragma unroll
    for (int j = 0; j < 8; ++j) xr[j] = aload(RollC + rr * 128 + kk8 + 16 * j);
    float s = 0.f, ss = 0.f;
#pragma unroll
    for (int j = 0; j < 8; ++j) {
      const unsigned lo = (unsigned)xr[j], hi = (unsigned)(xr[j] >> 32);
      const float v0 = bflo(lo), v1 = bfhi(lo), v2 = bflo(hi), v3 = bfhi(hi);
      s  += v0 + v1 + v2 + v3;
      ss += v0 * v0 + v1 * v1 + v2 * v2 + v3 * v3;
    }
#pragma unroll
    for (int m = 1; m < 16; m <<= 1) { s += __shfl_xor(s, m, 64); ss += __shfl_xor(ss, m, 64); }
    const float mu = s * (1.f / 512.f);
    const float rs = rsqrtf(ss * (1.f / 512.f) - mu * mu + 1e-5f);
#pragma unroll
    for (int j = 0; j < 8; ++j) {
      const int jj = kk8 + 16 * j;
      const f32x4 sc4 = *(const f32x4*)(lnSl + 4 * jj);
      const f32x4 bi4 = *(const f32x4*)(lnBl + 4 * jj);
      const unsigned lo = (unsigned)xr[j], hi = (unsigned)(xr[j] >> 32);
      const float a0 = (bflo(lo) - mu) * rs * sc4[0] + bi4[0];
      const float a1 = (bfhi(lo) - mu) * rs * sc4[1] + bi4[1];
      const float a2 = (bflo(hi) - mu) * rs * sc4[2] + bi4[2];
      const float a3 = (bfhi(hi) - mu) * rs * sc4[3] + bi4[3];
      *(unsigned long long*)(xarea + ((rr * 1024 + jj * 8) ^ ((rr & 7) << 4))) =
          (unsigned long long)pack2bf(a0, a1) | ((unsigned long long)pack2bf(a2, a3) << 32);
    }
  }
  __syncthreads();

  const int rA  = lane & 15;
  const int kg2 = lane >> 4;
  const int swz = (rA & 7) << 4;
  const int ab0 = rA * 1024 + kg2 * 16;
  const int ab1 = ab0 + 16384;

  float creg0 = 0.f, creg1 = 0.f;
  unsigned myC = 0;     // latched consumer progress (back-pressure)
  unsigned prodC = 0;   // latched producer flag
  const int lane15 = lane & 15;

#pragma unroll 1
  for (int t = 0; t < 2048; ++t) {
    // (a) back-pressure: Roll slot t&3 reusable when consumer prog >= t-4
    if (layer < 5 && t >= 5) {
      const unsigned need = (unsigned)(t - 4);
      while (!__all((int)(myC >= need))) {
        if (myC < need)
          myC = __hip_atomic_load(Prog + (layer + 1) * 16 + lane15,
                                  __ATOMIC_RELAXED, __HIP_MEMORY_SCOPE_AGENT);
        if (!__all((int)(myC >= need))) __builtin_amdgcn_s_sleep(1);
      }
    }

    // (b) own-layer barrier: peers stored h for step t (flag >= t+1)
    waitflags(Flg, layer * 16, (unsigned)(t + 1), lane);

    // (c) issue untagged h loads (8 u64/thread, LLC)
    const unsigned long long* hs = HstL + (size_t)(t & 1) * 4096;
    unsigned long long a[8];
#pragma unroll
    for (int it = 0; it < 8; ++it)
      a[it] = aload(hs + it * 512 + tid);

    // (c2) early producer wait (latched) + xr issue: flight hides under compute
    unsigned long long xr[8];
    if (layer > 0 && t < 2047) {
      const unsigned need = (unsigned)(t + 3);
      while (!__all((int)(prodC >= need))) {
        if (prodC < need)
          prodC = __hip_atomic_load(Flg + (layer - 1) * 16 + lane15,
                                    __ATOMIC_RELAXED, __HIP_MEMORY_SCOPE_AGENT);
        if (!__all((int)(prodC >= need))) __builtin_amdgcn_s_sleep(1);
      }
      const unsigned long long* RollC = Roll + (size_t)((layer - 1) * 4 + ((t + 1) & 3)) * 4096;
#pragma unroll
      for (int j = 0; j < 8; ++j) xr[j] = aload(RollC + rr * 128 + kk8 + 16 * j);
    }

    // (d) ih-MFMA from xarea overlaps load flight
    float xin0, xin1;
    f32x4 ai0 = {0.f,0.f,0.f,0.f}, ai1 = {0.f,0.f,0.f,0.f};
    if (layer > 0) {
      const unsigned xu = *(const unsigned*)(xarea + (((ub * 1024) + kpglob * 4) ^ ((ub & 7) << 4)));
      xin0 = bflo(xu); xin1 = bfhi(xu);
#pragma unroll
      for (int kk = 0; kk < 16; ++kk) {
        const i32x4 x0 = *(const i32x4*)(xarea + ((ab0 + kk * 64) ^ swz));
        const i32x4 x1 = *(const i32x4*)(xarea + ((ab1 + kk * 64) ^ swz));
        ai0 = __builtin_amdgcn_mfma_f32_16x16x32_bf16(__builtin_bit_cast(s16x8, x0), bfih[kk], ai0, 0, 0, 0);
        ai1 = __builtin_amdgcn_mfma_f32_16x16x32_bf16(__builtin_bit_cast(s16x8, x1), bfih[kk], ai1, 0, 0, 0);
      }
    } else { xin0 = xinc0; xin1 = xinc1; }

    // (e) stage h payloads into LDS (swizzled)
#pragma unroll
    for (int it = 0; it < 8; ++it) {
      const int flat = it * 512 + tid;
      const int q = flat >> 7, kp2 = flat & 127;
      *(unsigned long long*)(harea + ((q * 1024 + kp2 * 8) ^ ((q & 7) << 4))) = a[it];
    }
    __syncthreads();   // (1) h staged

    // hh-MFMA (per wave: its 16 cols x batch 0-31)
    f32x4 ah0 = {0.f,0.f,0.f,0.f}, ah1 = {0.f,0.f,0.f,0.f};
#pragma unroll
    for (int kk = 0; kk < 16; ++kk) {
      const i32x4 h0 = *(const i32x4*)(harea + ((ab0 + kk * 64) ^ swz));
      const i32x4 h1 = *(const i32x4*)(harea + ((ab1 + kk * 64) ^ swz));
      ah0 = __builtin_amdgcn_mfma_f32_16x16x32_bf16(__builtin_bit_cast(s16x8, h0), bfhh[kk], ah0, 0, 0, 0);
      ah1 = __builtin_amdgcn_mfma_f32_16x16x32_bf16(__builtin_bit_cast(s16x8, h1), bfhh[kk], ah1, 0, 0, 0);
    }
    const f32x4 acc0 = ai0 + ah0, acc1 = ai1 + ah1;
    // gacc disjoint from harea: write directly
    {
      float* gp = gacc + (gt * 32 + ch * 16 + rA) * 36 + kg2 * 4;
      *(f32x4*)gp        = acc0;          // batch kg2*4..+3
      *(f32x4*)(gp + 16) = acc1;          // batch 16+kg2*4..
    }
    __syncthreads();   // (3) gacc visible cross-wave

    float pre[4][2];
#pragma unroll
    for (int g = 0; g < 4; ++g)
#pragma unroll
      for (int c = 0; c < 2; ++c) {
        float vv = gacc[(g * 32 + 2 * jp + c) * 36 + ub] + bs[g][c];
        if (layer == 0) vv += ((const float*)smem)[g * 1024 + ub * 32 + 2 * jp + c];
        pre[g][c] = vv;
      }

    float i0 = sigm(pre[0][0]), ff0 = sigm(pre[1][0]), g0 = tanh_(pre[2][0]), o0 = sigm(pre[3][0]);
    creg0 = ff0 * creg0 + i0 * g0;
    float h0 = o0 * tanh_(creg0);
    float i1 = sigm(pre[0][1]), ff1 = sigm(pre[1][1]), g1 = tanh_(pre[2][1]), o1 = sigm(pre[3][1]);
    creg1 = ff1 * creg1 + i1 * g1;
    float h1 = o1 * tanh_(creg1);
    const float out0 = h0 + xin0, out1 = h1 + xin1;

    if (layer < 5) {
      astore32((unsigned*)(Roll + (size_t)(layer * 4 + (t & 3)) * 4096) + (ub << 8) + kpglob,
               pack2bf(out0, out1));
    } else {
      RB[((size_t)ub * 2048 + t) * 256 + kpglob] = pack2bf(out0, out1);
    }
    astore32((unsigned*)(HstL + (size_t)((t + 1) & 1) * 4096) + (ub << 8) + kpglob,
             pack2bf(h0, h1));

    __syncthreads();   // (4) drains our stores AND xr loads before flag
    if (tid == 0) {
      __hip_atomic_store(Flg + layer * 16 + w, (unsigned)(t + 2),
                         __ATOMIC_RELEASE, __HIP_MEMORY_SCOPE_AGENT);
      if (layer > 0 && t < 2047)
        astore32(Prog + layer * 16 + w, (unsigned)(t + 1));
    }

    // (k) in-register LN of row t+1 + stage into xarea (overlaps flag propagation)
    if (layer > 0 && t < 2047) {
      float s = 0.f, ss = 0.f;
#pragma unroll
      for (int j = 0; j < 8; ++j) {
        const unsigned lo = (unsigned)xr[j], hi = (unsigned)(xr[j] >> 32);
        const float v0 = bflo(lo), v1 = bfhi(lo), v2 = bflo(hi), v3 = bfhi(hi);
        s  += v0 + v1 + v2 + v3;
        ss += v0 * v0 + v1 * v1 + v2 * v2 + v3 * v3;
      }
#pragma unroll
      for (int m = 1; m < 16; m <<= 1) { s += __shfl_xor(s, m, 64); ss += __shfl_xor(ss, m, 64); }
      const float mu = s * (1.f / 512.f);
      const float rs = rsqrtf(ss * (1.f / 512.f) - mu * mu + 1e-5f);
#pragma unroll
      for (int j = 0; j < 8; ++j) {
        const int jj = kk8 + 16 * j;
        const f32x4 sc4 = *(const f32x4*)(lnSl + 4 * jj);
        const f32x4 bi4 = *(const f32x4*)(lnBl + 4 * jj);
        const unsigned lo = (unsigned)xr[j], hi = (unsigned)(xr[j] >> 32);
        const float a0 = (bflo(lo) - mu) * rs * sc4[0] + bi4[0];
        const float a1 = (bfhi(lo) - mu) * rs * sc4[1] + bi4[1];
        const float a2 = (bflo(hi) - mu) * rs * sc4[2] + bi4[2];
        const float a3 = (bfhi(hi) - mu) * rs * sc4[3] + bi4[3];
        *(unsigned long long*)(xarea + ((rr * 1024 + jj * 8) ^ ((rr & 7) << 4))) =
            (unsigned long long)pack2bf(a0, a1) | ((unsigned long long)pack2bf(a2, a3) << 32);
      }
    }

    __syncthreads();   // (5) xarea ready; gacc reads done before next write
  }
}

// ---------------- fused final LayerNorm + output head ----------------
__global__ __launch_bounds__(256) void k_lnout(const unsigned* __restrict__ Rin,
                                               const float* __restrict__ lnS,
                                               const float* __restrict__ lnB,
                                               const float* __restrict__ ow,
                                               const float* __restrict__ ob,
                                               float* __restrict__ y) {
  int row  = blockIdx.x * 4 + (threadIdx.x >> 6);
  int lane = threadIdx.x & 63;
  const i32x4 v = *(const i32x4*)(Rin + (size_t)row * 256 + lane * 4);
  float xv[8];
#pragma unroll
  for (int j = 0; j < 4; ++j) {
    unsigned u = (unsigned)v[j];
    xv[2*j]   = bflo(u);
    xv[2*j+1] = bfhi(u);
  }
  float s = 0.f, s2 = 0.f;
#pragma unroll
  for (int j = 0; j < 8; ++j) { s += xv[j]; s2 += xv[j] * xv[j]; }
#pragma unroll
  for (int m = 1; m < 64; m <<= 1) { s += __shfl_xor(s, m, 64); s2 += __shfl_xor(s2, m, 64); }
  float mu  = s * (1.f / 512.f);
  float var = s2 * (1.f / 512.f) - mu * mu;
  float rs  = rsqrtf(var + 1e-5f);
  const float* Sp = lnS + 5 * 512 + lane * 8;
  const float* Bp = lnB + 5 * 512 + lane * 8;
  const float* wp = ow + lane * 8;
  float acc = 0.f;
#pragma unroll
  for (int j = 0; j < 8; ++j)
    acc += ((xv[j] - mu) * rs * Sp[j] + Bp[j]) * wp[j];
#pragma unroll
  for (int m = 1; m < 64; m <<= 1) acc += __shfl_xor(acc, m, 64);
  if (lane == 0) y[row] = acc + ob[0];
}

extern "C" void kernel_launch(void* const* d_in, const int* in_sizes, int n_in,
                              void* d_out, int out_size, void* d_ws, size_t ws_size,
                              hipStream_t stream) {
  (void)in_sizes; (void)n_in; (void)out_size; (void)ws_size;
  const float* x   = (const float*)d_in[0];
  const float* ipw = (const float*)d_in[1];
  const float* ipb = (const float*)d_in[2];
  const float* Wih = (const float*)d_in[3];
  const float* Whh = (const float*)d_in[4];
  const float* bih = (const float*)d_in[5];
  const float* bhh = (const float*)d_in[6];
  const float* lnS = (const float*)d_in[7];
  const float* lnB = (const float*)d_in[8];
  const float* ow  = (const float*)d_in[9];
  const float* ob  = (const float*)d_in[10];
  float* y = (float*)d_out;

  char* ws = (char*)d_ws;
  unsigned* Flg             = (unsigned*)ws;                         // 384 B packed
  unsigned* Prog            = (unsigned*)(ws + 1024);                // 384 B packed
  float* XP                 = (float*)(ws + 32768);                  // 64 KB
  float* XG0                = (float*)(ws + 98304);                  // 256 KB
  unsigned long long* Hst   = (unsigned long long*)(ws + 360448);    // 384 KB
  unsigned long long* Roll  = (unsigned long long*)(ws + 753664);    // 640 KB
  unsigned* RB              = (unsigned*)(ws + 2097152);             // 67.1 MB

  hipMemsetAsync(ws, 0, 4096, stream);        // Flg + Prog
  k_inproj<<<64, 256, 0, stream>>>(x, ipw, ipb, XP);
  k_xg0<<<256, 256, 0, stream>>>(XP, Wih, bih, XG0);
  k_pipe<<<96, 512, 0, stream>>>(Wih, Whh, bih, bhh, lnS, lnB, XG0, XP,
                                 Hst, Roll, RB, Flg, Prog);
  k_lnout<<<16384, 256, 0, stream>>>(RB, lnS, lnB, ow, ob, y);
}

// Round 13
// 20903.792 us; speedup vs baseline: 1.2156x; 1.2156x over previous
//
#include <hip/hip_runtime.h>

typedef __attribute__((ext_vector_type(4))) int   i32x4;
typedef __attribute__((ext_vector_type(8))) short s16x8;
typedef __attribute__((ext_vector_type(4))) float f32x4;

__device__ __forceinline__ unsigned short f2bf(float f) {
  unsigned u = __float_as_uint(f);
  unsigned r = u + 0x7FFFu + ((u >> 16) & 1u);
  return (unsigned short)(r >> 16);
}
__device__ __forceinline__ unsigned pack2bf(float lo, float hi) {
  return (unsigned)f2bf(lo) | ((unsigned)f2bf(hi) << 16);
}
__device__ __forceinline__ float bflo(unsigned u){ return __uint_as_float(u << 16); }
__device__ __forceinline__ float bfhi(unsigned u){ return __uint_as_float(u & 0xFFFF0000u); }

__device__ __forceinline__ float sigm(float x){ return 1.0f / (1.0f + __expf(-x)); }
__device__ __forceinline__ float tanh_(float x){
  float ax = fabsf(x);
  float e  = __expf(-2.0f * ax);
  float t  = (1.0f - e) / (1.0f + e);
  return copysignf(t, x);
}

__device__ __forceinline__ unsigned long long aload(const unsigned long long* p) {
  return __hip_atomic_load(p, __ATOMIC_RELAXED, __HIP_MEMORY_SCOPE_AGENT);
}
__device__ __forceinline__ void astore32(unsigned* p, unsigned v) {
  __hip_atomic_store(p, v, __ATOMIC_RELAXED, __HIP_MEMORY_SCOPE_AGENT);
}

// 32-flag wait, packed layout: lanes 0-31 watch consecutive u32 (1-2 lines).
__device__ __forceinline__ void waitflags(const unsigned* F, int base, unsigned need, int lane) {
  const unsigned* p = F + base + (lane & 31);
  unsigned v = __hip_atomic_load(p, __ATOMIC_RELAXED, __HIP_MEMORY_SCOPE_AGENT);
  while (!__all((int)(v >= need))) {
    __builtin_amdgcn_s_sleep(1);
    v = __hip_atomic_load(p, __ATOMIC_RELAXED, __HIP_MEMORY_SCOPE_AGENT);
  }
}

// ---------------- input projection ----------------
__global__ __launch_bounds__(256) void k_inproj(const float* __restrict__ x,
                                                const float* __restrict__ w,
                                                const float* __restrict__ bb,
                                                float* __restrict__ XP) {
  int idx = blockIdx.x * 256 + threadIdx.x;
  int b = idx >> 9, j = idx & 511;
  float acc = bb[j];
#pragma unroll
  for (int k = 0; k < 12; ++k) acc += x[b * 12 + k] * w[j * 12 + k];
  XP[idx] = acc;
}

// ---------------- layer-0 input gates (constant over t) ----------------
__global__ __launch_bounds__(256) void k_xg0(const float* __restrict__ XP,
                                             const float* __restrict__ Wih,
                                             const float* __restrict__ bih,
                                             float* __restrict__ XG0) {
  int idx = blockIdx.x * 256 + threadIdx.x;
  int b = idx & 31;
  int r = idx >> 5;
  const float* wr = Wih + (size_t)r * 512;
  const float* xr = XP + b * 512;
  float acc = bih[r];
  for (int k = 0; k < 512; k += 4) {
    const f32x4 w4 = *(const f32x4*)(wr + k);
    const f32x4 x4 = *(const f32x4*)(xr + k);
    acc += w4[0]*x4[0] + w4[1]*x4[1] + w4[2]*x4[2] + w4[3]*x4[3];
  }
  XG0[b * 2048 + r] = acc;
}

// ---------------- 6-layer pipelined scan, layer-local flag sync ----------------
// R11 base (32 WGs x 256 thr per layer — R12 proved 16x512 worse) with the
// step tail reordered: phase-k LN moved BEFORE sync(4), so (a) store-ack
// drain overlaps LN VALU work, (b) sync(5) deleted — sync(4) is now the
// xarea/harea/gacc fence. 3 barriers/step. Hazard proof:
//   xarea: write(k,t) < sync4(t) < read(d,t+1)            OK
//   harea: read(hh,t) < sync4(t) < write(e,t+1)           OK
//   gacc:  read(cell,t) < sync4(t) < sync1(t+1) < write   OK
//   stores-vs-flag: sync4 drains vmcnt before tid0 publish OK
// Flag values identical to R11: publishes unconditional (max SF 2049,
// Prog 2047); waits own<=2048, producer<=2049, Prog<=2043 — terminate.
__global__ __launch_bounds__(256, 1) void k_pipe(
    const float* __restrict__ Wih, const float* __restrict__ Whh,
    const float* __restrict__ bih, const float* __restrict__ bhh,
    const float* __restrict__ lnS, const float* __restrict__ lnB,
    const float* __restrict__ XG0, const float* __restrict__ XP,
    unsigned long long* __restrict__ Hst,    // [6][2][4096] u64 (2 bf16-pairs)
    unsigned long long* __restrict__ Roll,   // [5][4][4096] u64
    unsigned* __restrict__ RB,               // [32][2048][256] layer-5 rows
    unsigned* __restrict__ Flg,              // [6][32] packed u32
    unsigned* __restrict__ Prog)             // [6][32] packed u32
{
  __shared__ char smem[74752];
  const int tid   = threadIdx.x;
  const int wgid  = blockIdx.x;
  const int layer = wgid >> 5;
  const int w     = wgid & 31;

  char* xarea = smem;            // 32 KB: LN'd input row (l>=1) / L0 statics
  char* harea = smem + 32768;    // 32 KB: staged h only
  float* gacc = (float*)(smem + 65536);   // [4][16][36] f32, disjoint
  const int lane = tid & 63;
  const int wv   = tid >> 6;     // wave = gate index
  const int j0   = w << 4;

  unsigned long long* HstL = Hst + layer * 8192;

  // ---- B-fragment preload ----
  s16x8 bfih[16], bfhh[16];
  {
    const int rcol = lane & 15;
    const int kg   = lane >> 4;
    const size_t rowbase = ((size_t)layer * 2048 + (size_t)(wv * 512 + j0 + rcol)) * 512;
    const float* ihr = Wih + rowbase;
    const float* hhr = Whh + rowbase;
#pragma unroll
    for (int kk = 0; kk < 16; ++kk) {
      const int k0 = kg * 8 + kk * 32;
      s16x8 v2;
#pragma unroll
      for (int j = 0; j < 8; ++j) v2[j] = (short)f2bf(hhr[k0 + j]);
      bfhh[kk] = v2;
      if (layer > 0) {
        s16x8 v1;
#pragma unroll
        for (int j = 0; j < 8; ++j) v1[j] = (short)f2bf(ihr[k0 + j]);
        bfih[kk] = v1;
      }
    }
  }

  const int ub = tid >> 3;            // batch row this thread updates (cell)
  const int jp = tid & 7;             // col-pair within WG
  const int kpglob = (j0 >> 1) + jp;  // global u32 pair index

  float bs[4][2];
#pragma unroll
  for (int g = 0; g < 4; ++g)
#pragma unroll
    for (int c = 0; c < 2; ++c) {
      const size_t r = (size_t)layer * 2048 + g * 512 + j0 + 2 * jp + c;
      float vv = bhh[r];
      if (layer > 0) vv += bih[r];    // L0: b_ih folded into XG0
      bs[g][c] = vv;
    }

  const float* lnSl = lnS + (layer - 1) * 512;   // valid only layer>0
  const float* lnBl = lnB + (layer - 1) * 512;

  if (layer == 0) {
    float* xg0s = (float*)smem;           // [4][32][16]
    float* xps  = (float*)(smem + 8192);  // [32][16]
    for (int i = tid; i < 2048; i += 256) {
      int g = i >> 9, b = (i >> 4) & 31, jl = i & 15;
      xg0s[i] = XG0[b * 2048 + g * 512 + j0 + jl];
    }
    for (int i = tid; i < 512; i += 256) {
      int b = i >> 4, jl = i & 15;
      xps[i] = XP[b * 512 + j0 + jl];
    }
  }

  // ---- h0 = 0 into slot 0; publish flag = 1 ----
  astore32((unsigned*)HstL + (ub << 8) + kpglob, 0u);
  __syncthreads();   // drains vmcnt: zero-stores visible before flag
  if (tid == 0)
    __hip_atomic_store(Flg + layer * 32 + w, 1u, __ATOMIC_RELEASE, __HIP_MEMORY_SCOPE_AGENT);

  float xinc0 = 0.f, xinc1 = 0.f;
  if (layer == 0) {
    const float* xps = (const float*)(smem + 8192);
    xinc0 = xps[ub * 16 + 2 * jp];
    xinc1 = xps[ub * 16 + 2 * jp + 1];
  }

  const int rr  = tid >> 3;   // LN row
  const int kk8 = tid & 7;    // LN u64 lane within row

  // ---- pre-loop blocking LN-stage of row 0 (layer>0): producer flag >= 2 ----
  if (layer > 0) {
    waitflags(Flg, (layer - 1) * 32, 2u, lane);
    const unsigned long long* RollC = Roll + (layer - 1) * 16384;   // slot 0
    unsigned long long xr[16];
#pragma unroll
    for (int j = 0; j < 16; ++j) xr[j] = aload(RollC + rr * 128 + kk8 + 8 * j);
    float s = 0.f, ss = 0.f;
#pragma unroll
    for (int j = 0; j < 16; ++j) {
      const unsigned lo = (unsigned)xr[j], hi = (unsigned)(xr[j] >> 32);
      const float v0 = bflo(lo), v1 = bfhi(lo), v2 = bflo(hi), v3 = bfhi(hi);
      s  += v0 + v1 + v2 + v3;
      ss += v0 * v0 + v1 * v1 + v2 * v2 + v3 * v3;
    }
#pragma unroll
    for (int m = 1; m < 8; m <<= 1) { s += __shfl_xor(s, m, 64); ss += __shfl_xor(ss, m, 64); }
    const float mu = s * (1.f / 512.f);
    const float rs = rsqrtf(ss * (1.f / 512.f) - mu * mu + 1e-5f);
#pragma unroll
    for (int j = 0; j < 16; ++j) {
      const int jj = kk8 + 8 * j;
      const f32x4 sc4 = *(const f32x4*)(lnSl + 4 * jj);
      const f32x4 bi4 = *(const f32x4*)(lnBl + 4 * jj);
      const unsigned lo = (unsigned)xr[j], hi = (unsigned)(xr[j] >> 32);
      const float a0 = (bflo(lo) - mu) * rs * sc4[0] + bi4[0];
      const float a1 = (bfhi(lo) - mu) * rs * sc4[1] + bi4[1];
      const float a2 = (bflo(hi) - mu) * rs * sc4[2] + bi4[2];
      const float a3 = (bfhi(hi) - mu) * rs * sc4[3] + bi4[3];
      *(unsigned long long*)(xarea + ((rr * 1024 + jj * 8) ^ ((rr & 7) << 4))) =
          (unsigned long long)pack2bf(a0, a1) | ((unsigned long long)pack2bf(a2, a3) << 32);
    }
  }
  __syncthreads();

  const int rA  = lane & 15;
  const int kg2 = lane >> 4;
  const int swz = (rA & 7) << 4;
  const int ab0 = rA * 1024 + kg2 * 16;
  const int ab1 = ab0 + 16384;

  float creg0 = 0.f, creg1 = 0.f;
  unsigned myC = 0;     // latched consumer progress (back-pressure)
  unsigned prodC = 0;   // latched producer flag
  const int lane31 = lane & 31;

#pragma unroll 1
  for (int t = 0; t < 2048; ++t) {
    // (a) back-pressure: Roll slot t&3 reusable when consumer prog >= t-4
    if (layer < 5 && t >= 5) {
      const unsigned need = (unsigned)(t - 4);
      while (!__all((int)(myC >= need))) {
        if (myC < need)
          myC = __hip_atomic_load(Prog + (layer + 1) * 32 + lane31,
                                  __ATOMIC_RELAXED, __HIP_MEMORY_SCOPE_AGENT);
        if (!__all((int)(myC >= need))) __builtin_amdgcn_s_sleep(1);
      }
    }

    // (b) own-layer barrier: peers stored h for step t (flag >= t+1)
    waitflags(Flg, layer * 32, (unsigned)(t + 1), lane);

    // (c) issue untagged h loads (16 u64/thread, LLC)
    const unsigned long long* hs = HstL + (size_t)(t & 1) * 4096;
    unsigned long long a[16];
#pragma unroll
    for (int it = 0; it < 16; ++it)
      a[it] = aload(hs + it * 256 + tid);

    // (c2) early producer wait (latched) + xr issue: flight hides under compute
    unsigned long long xr[16];
    if (layer > 0 && t < 2047) {
      const unsigned need = (unsigned)(t + 3);
      while (!__all((int)(prodC >= need))) {
        if (prodC < need)
          prodC = __hip_atomic_load(Flg + (layer - 1) * 32 + lane31,
                                    __ATOMIC_RELAXED, __HIP_MEMORY_SCOPE_AGENT);
        if (!__all((int)(prodC >= need))) __builtin_amdgcn_s_sleep(1);
      }
      const unsigned long long* RollC = Roll + (size_t)((layer - 1) * 4 + ((t + 1) & 3)) * 4096;
#pragma unroll
      for (int j = 0; j < 16; ++j) xr[j] = aload(RollC + rr * 128 + kk8 + 8 * j);
    }

    // (d) ih-MFMA from xarea overlaps load flight
    float xin0, xin1;
    f32x4 ai0 = {0.f,0.f,0.f,0.f}, ai1 = {0.f,0.f,0.f,0.f};
    if (layer > 0) {
      const unsigned xu = *(const unsigned*)(xarea + (((ub * 1024) + kpglob * 4) ^ ((ub & 7) << 4)));
      xin0 = bflo(xu); xin1 = bfhi(xu);
#pragma unroll
      for (int kk = 0; kk < 16; ++kk) {
        const i32x4 x0 = *(const i32x4*)(xarea + ((ab0 + kk * 64) ^ swz));
        const i32x4 x1 = *(const i32x4*)(xarea + ((ab1 + kk * 64) ^ swz));
        ai0 = __builtin_amdgcn_mfma_f32_16x16x32_bf16(__builtin_bit_cast(s16x8, x0), bfih[kk], ai0, 0, 0, 0);
        ai1 = __builtin_amdgcn_mfma_f32_16x16x32_bf16(__builtin_bit_cast(s16x8, x1), bfih[kk], ai1, 0, 0, 0);
      }
    } else { xin0 = xinc0; xin1 = xinc1; }

    // (e) stage h payloads into LDS (swizzled)
#pragma unroll
    for (int it = 0; it < 16; ++it) {
      const int flat = it * 256 + tid;
      const int q = flat >> 7, kp2 = flat & 127;
      *(unsigned long long*)(harea + ((q * 1024 + kp2 * 8) ^ ((q & 7) << 4))) = a[it];
    }
    __syncthreads();   // (1) h staged

    f32x4 acc0, acc1;
    if (layer > 0) {
      f32x4 ah0 = {0.f,0.f,0.f,0.f}, ah1 = {0.f,0.f,0.f,0.f};
#pragma unroll
      for (int kk = 0; kk < 16; ++kk) {
        const i32x4 h0 = *(const i32x4*)(harea + ((ab0 + kk * 64) ^ swz));
        const i32x4 h1 = *(const i32x4*)(harea + ((ab1 + kk * 64) ^ swz));
        ah0 = __builtin_amdgcn_mfma_f32_16x16x32_bf16(__builtin_bit_cast(s16x8, h0), bfhh[kk], ah0, 0, 0, 0);
        ah1 = __builtin_amdgcn_mfma_f32_16x16x32_bf16(__builtin_bit_cast(s16x8, h1), bfhh[kk], ah1, 0, 0, 0);
      }
      acc0 = ai0 + ah0; acc1 = ai1 + ah1;
    } else {
      f32x4 a0a = {0.f,0.f,0.f,0.f}, a1a = {0.f,0.f,0.f,0.f};
      f32x4 a0b = {0.f,0.f,0.f,0.f}, a1b = {0.f,0.f,0.f,0.f};
#pragma unroll
      for (int kk = 0; kk < 8; ++kk) {
        const i32x4 h0a = *(const i32x4*)(harea + ((ab0 + kk * 64) ^ swz));
        const i32x4 h1a = *(const i32x4*)(harea + ((ab1 + kk * 64) ^ swz));
        const i32x4 h0b = *(const i32x4*)(harea + ((ab0 + (kk + 8) * 64) ^ swz));
        const i32x4 h1b = *(const i32x4*)(harea + ((ab1 + (kk + 8) * 64) ^ swz));
        a0a = __builtin_amdgcn_mfma_f32_16x16x32_bf16(__builtin_bit_cast(s16x8, h0a), bfhh[kk], a0a, 0, 0, 0);
        a1a = __builtin_amdgcn_mfma_f32_16x16x32_bf16(__builtin_bit_cast(s16x8, h1a), bfhh[kk], a1a, 0, 0, 0);
        a0b = __builtin_amdgcn_mfma_f32_16x16x32_bf16(__builtin_bit_cast(s16x8, h0b), bfhh[kk + 8], a0b, 0, 0, 0);
        a1b = __builtin_amdgcn_mfma_f32_16x16x32_bf16(__builtin_bit_cast(s16x8, h1b), bfhh[kk + 8], a1b, 0, 0, 0);
      }
      acc0 = a0a + a0b; acc1 = a1a + a1b;
    }
    // gacc disjoint from harea: write directly
    {
      float* gp = gacc + (wv * 16 + rA) * 36 + kg2 * 4;
      *(f32x4*)gp        = acc0;
      *(f32x4*)(gp + 16) = acc1;
    }
    __syncthreads();   // (3) gacc visible cross-wave

    float pre[4][2];
#pragma unroll
    for (int g = 0; g < 4; ++g)
#pragma unroll
      for (int c = 0; c < 2; ++c) {
        float vv = gacc[(g * 16 + 2 * jp + c) * 36 + ub] + bs[g][c];
        if (layer == 0) vv += ((const float*)smem)[(g * 32 + ub) * 16 + 2 * jp + c];
        pre[g][c] = vv;
      }

    float i0 = sigm(pre[0][0]), ff0 = sigm(pre[1][0]), g0 = tanh_(pre[2][0]), o0 = sigm(pre[3][0]);
    creg0 = ff0 * creg0 + i0 * g0;
    float h0 = o0 * tanh_(creg0);
    float i1 = sigm(pre[0][1]), ff1 = sigm(pre[1][1]), g1 = tanh_(pre[2][1]), o1 = sigm(pre[3][1]);
    creg1 = ff1 * creg1 + i1 * g1;
    float h1 = o1 * tanh_(creg1);
    const float out0 = h0 + xin0, out1 = h1 + xin1;

    if (layer < 5) {
      astore32((unsigned*)(Roll + (size_t)(layer * 4 + (t & 3)) * 4096) + (ub << 8) + kpglob,
               pack2bf(out0, out1));
    } else {
      RB[((size_t)ub * 2048 + t) * 256 + kpglob] = pack2bf(out0, out1);
    }
    astore32((unsigned*)(HstL + (size_t)((t + 1) & 1) * 4096) + (ub << 8) + kpglob,
             pack2bf(h0, h1));

    // (k) in-register LN of row t+1 + stage into xarea — BEFORE the drain:
    // LN VALU work overlaps the store-acks; xarea reads of step t all
    // completed before sync(1), so writing here is WG-safe.
    if (layer > 0 && t < 2047) {
      float s = 0.f, ss = 0.f;
#pragma unroll
      for (int j = 0; j < 16; ++j) {
        const unsigned lo = (unsigned)xr[j], hi = (unsigned)(xr[j] >> 32);
        const float v0 = bflo(lo), v1 = bfhi(lo), v2 = bflo(hi), v3 = bfhi(hi);
        s  += v0 + v1 + v2 + v3;
        ss += v0 * v0 + v1 * v1 + v2 * v2 + v3 * v3;
      }
#pragma unroll
      for (int m = 1; m < 8; m <<= 1) { s += __shfl_xor(s, m, 64); ss += __shfl_xor(ss, m, 64); }
      const float mu = s * (1.f / 512.f);
      const float rs = rsqrtf(ss * (1.f / 512.f) - mu * mu + 1e-5f);
#pragma unroll
      for (int j = 0; j < 16; ++j) {
        const int jj = kk8 + 8 * j;
        const f32x4 sc4 = *(const f32x4*)(lnSl + 4 * jj);
        const f32x4 bi4 = *(const f32x4*)(lnBl + 4 * jj);
        const unsigned lo = (unsigned)xr[j], hi = (unsigned)(xr[j] >> 32);
        const float a0 = (bflo(lo) - mu) * rs * sc4[0] + bi4[0];
        const float a1 = (bfhi(lo) - mu) * rs * sc4[1] + bi4[1];
        const float a2 = (bflo(hi) - mu) * rs * sc4[2] + bi4[2];
        const float a3 = (bfhi(hi) - mu) * rs * sc4[3] + bi4[3];
        *(unsigned long long*)(xarea + ((rr * 1024 + jj * 8) ^ ((rr & 7) << 4))) =
            (unsigned long long)pack2bf(a0, a1) | ((unsigned long long)pack2bf(a2, a3) << 32);
      }
    }

    __syncthreads();   // (4) drains stores (acks overlapped by LN above);
                       //     fences xarea/harea/gacc for next iteration
    if (tid == 0) {
      __hip_atomic_store(Flg + layer * 32 + w, (unsigned)(t + 2),
                         __ATOMIC_RELEASE, __HIP_MEMORY_SCOPE_AGENT);
      if (layer > 0 && t < 2047)
        astore32(Prog + layer * 32 + w, (unsigned)(t + 1));
    }
  }
}

// ---------------- fused final LayerNorm + output head ----------------
__global__ __launch_bounds__(256) void k_lnout(const unsigned* __restrict__ Rin,
                                               const float* __restrict__ lnS,
                                               const float* __restrict__ lnB,
                                               const float* __restrict__ ow,
                                               const float* __restrict__ ob,
                                               float* __restrict__ y) {
  int row  = blockIdx.x * 4 + (threadIdx.x >> 6);
  int lane = threadIdx.x & 63;
  const i32x4 v = *(const i32x4*)(Rin + (size_t)row * 256 + lane * 4);
  float xv[8];
#pragma unroll
  for (int j = 0; j < 4; ++j) {
    unsigned u = (unsigned)v[j];
    xv[2*j]   = bflo(u);
    xv[2*j+1] = bfhi(u);
  }
  float s = 0.f, s2 = 0.f;
#pragma unroll
  for (int j = 0; j < 8; ++j) { s += xv[j]; s2 += xv[j] * xv[j]; }
#pragma unroll
  for (int m = 1; m < 64; m <<= 1) { s += __shfl_xor(s, m, 64); s2 += __shfl_xor(s2, m, 64); }
  float mu  = s * (1.f / 512.f);
  float var = s2 * (1.f / 512.f) - mu * mu;
  float rs  = rsqrtf(var + 1e-5f);
  const float* Sp = lnS + 5 * 512 + lane * 8;
  const float* Bp = lnB + 5 * 512 + lane * 8;
  const float* wp = ow + lane * 8;
  float acc = 0.f;
#pragma unroll
  for (int j = 0; j < 8; ++j)
    acc += ((xv[j] - mu) * rs * Sp[j] + Bp[j]) * wp[j];
#pragma unroll
  for (int m = 1; m < 64; m <<= 1) acc += __shfl_xor(acc, m, 64);
  if (lane == 0) y[row] = acc + ob[0];
}

extern "C" void kernel_launch(void* const* d_in, const int* in_sizes, int n_in,
                              void* d_out, int out_size, void* d_ws, size_t ws_size,
                              hipStream_t stream) {
  (void)in_sizes; (void)n_in; (void)out_size; (void)ws_size;
  const float* x   = (const float*)d_in[0];
  const float* ipw = (const float*)d_in[1];
  const float* ipb = (const float*)d_in[2];
  const float* Wih = (const float*)d_in[3];
  const float* Whh = (const float*)d_in[4];
  const float* bih = (const float*)d_in[5];
  const float* bhh = (const float*)d_in[6];
  const float* lnS = (const float*)d_in[7];
  const float* lnB = (const float*)d_in[8];
  const float* ow  = (const float*)d_in[9];
  const float* ob  = (const float*)d_in[10];
  float* y = (float*)d_out;

  char* ws = (char*)d_ws;
  unsigned* Flg             = (unsigned*)ws;                         // 768 B packed
  unsigned* Prog            = (unsigned*)(ws + 1024);                // 768 B packed
  float* XP                 = (float*)(ws + 32768);                  // 64 KB
  float* XG0                = (float*)(ws + 98304);                  // 256 KB
  unsigned long long* Hst   = (unsigned long long*)(ws + 360448);    // 384 KB
  unsigned long long* Roll  = (unsigned long long*)(ws + 753664);    // 640 KB
  unsigned* RB              = (unsigned*)(ws + 2097152);             // 67.1 MB

  hipMemsetAsync(ws, 0, 4096, stream);        // Flg + Prog
  k_inproj<<<64, 256, 0, stream>>>(x, ipw, ipb, XP);
  k_xg0<<<256, 256, 0, stream>>>(XP, Wih, bih, XG0);
  k_pipe<<<192, 256, 0, stream>>>(Wih, Whh, bih, bhh, lnS, lnB, XG0, XP,
                                  Hst, Roll, RB, Flg, Prog);
  k_lnout<<<16384, 256, 0, stream>>>(RB, lnS, lnB, ow, ob, y);
}

// Round 14
// 16319.089 us; speedup vs baseline: 1.5571x; 1.2809x over previous
//
#include <hip/hip_runtime.h>

typedef __attribute__((ext_vector_type(4))) int   i32x4;
typedef __attribute__((ext_vector_type(8))) short s16x8;
typedef __attribute__((ext_vector_type(4))) float f32x4;

__device__ __forceinline__ unsigned short f2bf(float f) {
  unsigned u = __float_as_uint(f);
  unsigned r = u + 0x7FFFu + ((u >> 16) & 1u);
  return (unsigned short)(r >> 16);
}
__device__ __forceinline__ unsigned pack2bf(float lo, float hi) {
  return (unsigned)f2bf(lo) | ((unsigned)f2bf(hi) << 16);
}
__device__ __forceinline__ float bflo(unsigned u){ return __uint_as_float(u << 16); }
__device__ __forceinline__ float bfhi(unsigned u){ return __uint_as_float(u & 0xFFFF0000u); }

__device__ __forceinline__ float sigm(float x){ return 1.0f / (1.0f + __expf(-x)); }
__device__ __forceinline__ float tanh_(float x){
  float ax = fabsf(x);
  float e  = __expf(-2.0f * ax);
  float t  = (1.0f - e) / (1.0f + e);
  return copysignf(t, x);
}

__device__ __forceinline__ unsigned long long aload(const unsigned long long* p) {
  return __hip_atomic_load(p, __ATOMIC_RELAXED, __HIP_MEMORY_SCOPE_AGENT);
}
__device__ __forceinline__ void astore32(unsigned* p, unsigned v) {
  __hip_atomic_store(p, v, __ATOMIC_RELAXED, __HIP_MEMORY_SCOPE_AGENT);
}

// 32-flag wait, packed layout: lanes 0-31 watch consecutive u32 (1-2 lines).
__device__ __forceinline__ void waitflags(const unsigned* F, int base, unsigned need, int lane) {
  const unsigned* p = F + base + (lane & 31);
  unsigned v = __hip_atomic_load(p, __ATOMIC_RELAXED, __HIP_MEMORY_SCOPE_AGENT);
  while (!__all((int)(v >= need))) {
    __builtin_amdgcn_s_sleep(1);
    v = __hip_atomic_load(p, __ATOMIC_RELAXED, __HIP_MEMORY_SCOPE_AGENT);
  }
}

// ---------------- input projection ----------------
__global__ __launch_bounds__(256) void k_inproj(const float* __restrict__ x,
                                                const float* __restrict__ w,
                                                const float* __restrict__ bb,
                                                float* __restrict__ XP) {
  int idx = blockIdx.x * 256 + threadIdx.x;
  int b = idx >> 9, j = idx & 511;
  float acc = bb[j];
#pragma unroll
  for (int k = 0; k < 12; ++k) acc += x[b * 12 + k] * w[j * 12 + k];
  XP[idx] = acc;
}

// ---------------- layer-0 input gates (constant over t) ----------------
__global__ __launch_bounds__(256) void k_xg0(const float* __restrict__ XP,
                                             const float* __restrict__ Wih,
                                             const float* __restrict__ bih,
                                             float* __restrict__ XG0) {
  int idx = blockIdx.x * 256 + threadIdx.x;
  int b = idx & 31;
  int r = idx >> 5;
  const float* wr = Wih + (size_t)r * 512;
  const float* xr = XP + b * 512;
  float acc = bih[r];
  for (int k = 0; k < 512; k += 4) {
    const f32x4 w4 = *(const f32x4*)(wr + k);
    const f32x4 x4 = *(const f32x4*)(xr + k);
    acc += w4[0]*x4[0] + w4[1]*x4[1] + w4[2]*x4[2] + w4[3]*x4[3];
  }
  XG0[b * 2048 + r] = acc;
}

// ---------------- 6-layer pipelined scan, layer-local flag sync ----------------
// R11 configuration (session best, 16.67 ms): 32 WGs x 256 thr per layer;
// early xr issue; latched producer flag; de-aliased gacc; packed flags;
// publish IMMEDIATELY after drain (R13 showed LN-before-publish delays peers);
// LN after publish overlaps flag propagation. Publishes unconditional
// (max SF 2049, Prog 2047); waits own<=2048, producer<=2049, Prog<=2043.
__global__ __launch_bounds__(256, 1) void k_pipe(
    const float* __restrict__ Wih, const float* __restrict__ Whh,
    const float* __restrict__ bih, const float* __restrict__ bhh,
    const float* __restrict__ lnS, const float* __restrict__ lnB,
    const float* __restrict__ XG0, const float* __restrict__ XP,
    unsigned long long* __restrict__ Hst,    // [6][2][4096] u64 (2 bf16-pairs)
    unsigned long long* __restrict__ Roll,   // [5][4][4096] u64
    unsigned* __restrict__ RB,               // [32][2048][256] layer-5 rows
    unsigned* __restrict__ Flg,              // [6][32] packed u32
    unsigned* __restrict__ Prog)             // [6][32] packed u32
{
  __shared__ char smem[74752];
  const int tid   = threadIdx.x;
  const int wgid  = blockIdx.x;
  const int layer = wgid >> 5;
  const int w     = wgid & 31;

  char* xarea = smem;            // 32 KB: LN'd input row (l>=1) / L0 statics
  char* harea = smem + 32768;    // 32 KB: staged h only
  float* gacc = (float*)(smem + 65536);   // [4][16][36] f32, disjoint
  const int lane = tid & 63;
  const int wv   = tid >> 6;     // wave = gate index
  const int j0   = w << 4;

  unsigned long long* HstL = Hst + layer * 8192;

  // ---- B-fragment preload ----
  s16x8 bfih[16], bfhh[16];
  {
    const int rcol = lane & 15;
    const int kg   = lane >> 4;
    const size_t rowbase = ((size_t)layer * 2048 + (size_t)(wv * 512 + j0 + rcol)) * 512;
    const float* ihr = Wih + rowbase;
    const float* hhr = Whh + rowbase;
#pragma unroll
    for (int kk = 0; kk < 16; ++kk) {
      const int k0 = kg * 8 + kk * 32;
      s16x8 v2;
#pragma unroll
      for (int j = 0; j < 8; ++j) v2[j] = (short)f2bf(hhr[k0 + j]);
      bfhh[kk] = v2;
      if (layer > 0) {
        s16x8 v1;
#pragma unroll
        for (int j = 0; j < 8; ++j) v1[j] = (short)f2bf(ihr[k0 + j]);
        bfih[kk] = v1;
      }
    }
  }

  const int ub = tid >> 3;            // batch row this thread updates (cell)
  const int jp = tid & 7;             // col-pair within WG
  const int kpglob = (j0 >> 1) + jp;  // global u32 pair index

  float bs[4][2];
#pragma unroll
  for (int g = 0; g < 4; ++g)
#pragma unroll
    for (int c = 0; c < 2; ++c) {
      const size_t r = (size_t)layer * 2048 + g * 512 + j0 + 2 * jp + c;
      float vv = bhh[r];
      if (layer > 0) vv += bih[r];    // L0: b_ih folded into XG0
      bs[g][c] = vv;
    }

  const float* lnSl = lnS + (layer - 1) * 512;   // valid only layer>0
  const float* lnBl = lnB + (layer - 1) * 512;

  if (layer == 0) {
    float* xg0s = (float*)smem;           // [4][32][16]
    float* xps  = (float*)(smem + 8192);  // [32][16]
    for (int i = tid; i < 2048; i += 256) {
      int g = i >> 9, b = (i >> 4) & 31, jl = i & 15;
      xg0s[i] = XG0[b * 2048 + g * 512 + j0 + jl];
    }
    for (int i = tid; i < 512; i += 256) {
      int b = i >> 4, jl = i & 15;
      xps[i] = XP[b * 512 + j0 + jl];
    }
  }

  // ---- h0 = 0 into slot 0; publish flag = 1 ----
  astore32((unsigned*)HstL + (ub << 8) + kpglob, 0u);
  __syncthreads();   // drains vmcnt: zero-stores visible before flag
  if (tid == 0)
    __hip_atomic_store(Flg + layer * 32 + w, 1u, __ATOMIC_RELEASE, __HIP_MEMORY_SCOPE_AGENT);

  float xinc0 = 0.f, xinc1 = 0.f;
  if (layer == 0) {
    const float* xps = (const float*)(smem + 8192);
    xinc0 = xps[ub * 16 + 2 * jp];
    xinc1 = xps[ub * 16 + 2 * jp + 1];
  }

  const int rr  = tid >> 3;   // LN row
  const int kk8 = tid & 7;    // LN u64 lane within row

  // ---- pre-loop blocking LN-stage of row 0 (layer>0): producer flag >= 2 ----
  if (layer > 0) {
    waitflags(Flg, (layer - 1) * 32, 2u, lane);
    const unsigned long long* RollC = Roll + (layer - 1) * 16384;   // slot 0
    unsigned long long xr[16];
#pragma unroll
    for (int j = 0; j < 16; ++j) xr[j] = aload(RollC + rr * 128 + kk8 + 8 * j);
    float s = 0.f, ss = 0.f;
#pragma unroll
    for (int j = 0; j < 16; ++j) {
      const unsigned lo = (unsigned)xr[j], hi = (unsigned)(xr[j] >> 32);
      const float v0 = bflo(lo), v1 = bfhi(lo), v2 = bflo(hi), v3 = bfhi(hi);
      s  += v0 + v1 + v2 + v3;
      ss += v0 * v0 + v1 * v1 + v2 * v2 + v3 * v3;
    }
#pragma unroll
    for (int m = 1; m < 8; m <<= 1) { s += __shfl_xor(s, m, 64); ss += __shfl_xor(ss, m, 64); }
    const float mu = s * (1.f / 512.f);
    const float rs = rsqrtf(ss * (1.f / 512.f) - mu * mu + 1e-5f);
#pragma unroll
    for (int j = 0; j < 16; ++j) {
      const int jj = kk8 + 8 * j;
      const f32x4 sc4 = *(const f32x4*)(lnSl + 4 * jj);
      const f32x4 bi4 = *(const f32x4*)(lnBl + 4 * jj);
      const unsigned lo = (unsigned)xr[j], hi = (unsigned)(xr[j] >> 32);
      const float a0 = (bflo(lo) - mu) * rs * sc4[0] + bi4[0];
      const float a1 = (bfhi(lo) - mu) * rs * sc4[1] + bi4[1];
      const float a2 = (bflo(hi) - mu) * rs * sc4[2] + bi4[2];
      const float a3 = (bfhi(hi) - mu) * rs * sc4[3] + bi4[3];
      *(unsigned long long*)(xarea + ((rr * 1024 + jj * 8) ^ ((rr & 7) << 4))) =
          (unsigned long long)pack2bf(a0, a1) | ((unsigned long long)pack2bf(a2, a3) << 32);
    }
  }
  __syncthreads();

  const int rA  = lane & 15;
  const int kg2 = lane >> 4;
  const int swz = (rA & 7) << 4;
  const int ab0 = rA * 1024 + kg2 * 16;
  const int ab1 = ab0 + 16384;

  float creg0 = 0.f, creg1 = 0.f;
  unsigned myC = 0;     // latched consumer progress (back-pressure)
  unsigned prodC = 0;   // latched producer flag
  const int lane31 = lane & 31;

#pragma unroll 1
  for (int t = 0; t < 2048; ++t) {
    // (a) back-pressure: Roll slot t&3 reusable when consumer prog >= t-4
    if (layer < 5 && t >= 5) {
      const unsigned need = (unsigned)(t - 4);
      while (!__all((int)(myC >= need))) {
        if (myC < need)
          myC = __hip_atomic_load(Prog + (layer + 1) * 32 + lane31,
                                  __ATOMIC_RELAXED, __HIP_MEMORY_SCOPE_AGENT);
        if (!__all((int)(myC >= need))) __builtin_amdgcn_s_sleep(1);
      }
    }

    // (b) own-layer barrier: peers stored h for step t (flag >= t+1)
    waitflags(Flg, layer * 32, (unsigned)(t + 1), lane);

    // (c) issue untagged h loads (16 u64/thread, LLC)
    const unsigned long long* hs = HstL + (size_t)(t & 1) * 4096;
    unsigned long long a[16];
#pragma unroll
    for (int it = 0; it < 16; ++it)
      a[it] = aload(hs + it * 256 + tid);

    // (c2) early producer wait (latched) + xr issue: flight hides under compute
    unsigned long long xr[16];
    if (layer > 0 && t < 2047) {
      const unsigned need = (unsigned)(t + 3);
      while (!__all((int)(prodC >= need))) {
        if (prodC < need)
          prodC = __hip_atomic_load(Flg + (layer - 1) * 32 + lane31,
                                    __ATOMIC_RELAXED, __HIP_MEMORY_SCOPE_AGENT);
        if (!__all((int)(prodC >= need))) __builtin_amdgcn_s_sleep(1);
      }
      const unsigned long long* RollC = Roll + (size_t)((layer - 1) * 4 + ((t + 1) & 3)) * 4096;
#pragma unroll
      for (int j = 0; j < 16; ++j) xr[j] = aload(RollC + rr * 128 + kk8 + 8 * j);
    }

    // (d) ih-MFMA from xarea overlaps load flight
    float xin0, xin1;
    f32x4 ai0 = {0.f,0.f,0.f,0.f}, ai1 = {0.f,0.f,0.f,0.f};
    if (layer > 0) {
      const unsigned xu = *(const unsigned*)(xarea + (((ub * 1024) + kpglob * 4) ^ ((ub & 7) << 4)));
      xin0 = bflo(xu); xin1 = bfhi(xu);
#pragma unroll
      for (int kk = 0; kk < 16; ++kk) {
        const i32x4 x0 = *(const i32x4*)(xarea + ((ab0 + kk * 64) ^ swz));
        const i32x4 x1 = *(const i32x4*)(xarea + ((ab1 + kk * 64) ^ swz));
        ai0 = __builtin_amdgcn_mfma_f32_16x16x32_bf16(__builtin_bit_cast(s16x8, x0), bfih[kk], ai0, 0, 0, 0);
        ai1 = __builtin_amdgcn_mfma_f32_16x16x32_bf16(__builtin_bit_cast(s16x8, x1), bfih[kk], ai1, 0, 0, 0);
      }
    } else { xin0 = xinc0; xin1 = xinc1; }

    // (e) stage h payloads into LDS (swizzled)
#pragma unroll
    for (int it = 0; it < 16; ++it) {
      const int flat = it * 256 + tid;
      const int q = flat >> 7, kp2 = flat & 127;
      *(unsigned long long*)(harea + ((q * 1024 + kp2 * 8) ^ ((q & 7) << 4))) = a[it];
    }
    __syncthreads();   // (1) h staged

    f32x4 acc0, acc1;
    if (layer > 0) {
      f32x4 ah0 = {0.f,0.f,0.f,0.f}, ah1 = {0.f,0.f,0.f,0.f};
#pragma unroll
      for (int kk = 0; kk < 16; ++kk) {
        const i32x4 h0 = *(const i32x4*)(harea + ((ab0 + kk * 64) ^ swz));
        const i32x4 h1 = *(const i32x4*)(harea + ((ab1 + kk * 64) ^ swz));
        ah0 = __builtin_amdgcn_mfma_f32_16x16x32_bf16(__builtin_bit_cast(s16x8, h0), bfhh[kk], ah0, 0, 0, 0);
        ah1 = __builtin_amdgcn_mfma_f32_16x16x32_bf16(__builtin_bit_cast(s16x8, h1), bfhh[kk], ah1, 0, 0, 0);
      }
      acc0 = ai0 + ah0; acc1 = ai1 + ah1;
    } else {
      f32x4 a0a = {0.f,0.f,0.f,0.f}, a1a = {0.f,0.f,0.f,0.f};
      f32x4 a0b = {0.f,0.f,0.f,0.f}, a1b = {0.f,0.f,0.f,0.f};
#pragma unroll
      for (int kk = 0; kk < 8; ++kk) {
        const i32x4 h0a = *(const i32x4*)(harea + ((ab0 + kk * 64) ^ swz));
        const i32x4 h1a = *(const i32x4*)(harea + ((ab1 + kk * 64) ^ swz));
        const i32x4 h0b = *(const i32x4*)(harea + ((ab0 + (kk + 8) * 64) ^ swz));
        const i32x4 h1b = *(const i32x4*)(harea + ((ab1 + (kk + 8) * 64) ^ swz));
        a0a = __builtin_amdgcn_mfma_f32_16x16x32_bf16(__builtin_bit_cast(s16x8, h0a), bfhh[kk], a0a, 0, 0, 0);
        a1a = __builtin_amdgcn_mfma_f32_16x16x32_bf16(__builtin_bit_cast(s16x8, h1a), bfhh[kk], a1a, 0, 0, 0);
        a0b = __builtin_amdgcn_mfma_f32_16x16x32_bf16(__builtin_bit_cast(s16x8, h0b), bfhh[kk + 8], a0b, 0, 0, 0);
        a1b = __builtin_amdgcn_mfma_f32_16x16x32_bf16(__builtin_bit_cast(s16x8, h1b), bfhh[kk + 8], a1b, 0, 0, 0);
      }
      acc0 = a0a + a0b; acc1 = a1a + a1b;
    }
    // gacc disjoint from harea: write directly
    {
      float* gp = gacc + (wv * 16 + rA) * 36 + kg2 * 4;
      *(f32x4*)gp        = acc0;
      *(f32x4*)(gp + 16) = acc1;
    }
    __syncthreads();   // (3) gacc visible cross-wave

    float pre[4][2];
#pragma unroll
    for (int g = 0; g < 4; ++g)
#pragma unroll
      for (int c = 0; c < 2; ++c) {
        float vv = gacc[(g * 16 + 2 * jp + c) * 36 + ub] + bs[g][c];
        if (layer == 0) vv += ((const float*)smem)[(g * 32 + ub) * 16 + 2 * jp + c];
        pre[g][c] = vv;
      }

    float i0 = sigm(pre[0][0]), ff0 = sigm(pre[1][0]), g0 = tanh_(pre[2][0]), o0 = sigm(pre[3][0]);
    creg0 = ff0 * creg0 + i0 * g0;
    float h0 = o0 * tanh_(creg0);
    float i1 = sigm(pre[0][1]), ff1 = sigm(pre[1][1]), g1 = tanh_(pre[2][1]), o1 = sigm(pre[3][1]);
    creg1 = ff1 * creg1 + i1 * g1;
    float h1 = o1 * tanh_(creg1);
    const float out0 = h0 + xin0, out1 = h1 + xin1;

    if (layer < 5) {
      astore32((unsigned*)(Roll + (size_t)(layer * 4 + (t & 3)) * 4096) + (ub << 8) + kpglob,
               pack2bf(out0, out1));
    } else {
      RB[((size_t)ub * 2048 + t) * 256 + kpglob] = pack2bf(out0, out1);
    }
    astore32((unsigned*)(HstL + (size_t)((t + 1) & 1) * 4096) + (ub << 8) + kpglob,
             pack2bf(h0, h1));

    __syncthreads();   // (4) drains our stores AND xr loads before flag
    if (tid == 0) {
      __hip_atomic_store(Flg + layer * 32 + w, (unsigned)(t + 2),
                         __ATOMIC_RELEASE, __HIP_MEMORY_SCOPE_AGENT);
      if (layer > 0 && t < 2047)
        astore32(Prog + layer * 32 + w, (unsigned)(t + 1));
    }

    // (k) in-register LN of row t+1 + stage into xarea (overlaps flag propagation)
    if (layer > 0 && t < 2047) {
      float s = 0.f, ss = 0.f;
#pragma unroll
      for (int j = 0; j < 16; ++j) {
        const unsigned lo = (unsigned)xr[j], hi = (unsigned)(xr[j] >> 32);
        const float v0 = bflo(lo), v1 = bfhi(lo), v2 = bflo(hi), v3 = bfhi(hi);
        s  += v0 + v1 + v2 + v3;
        ss += v0 * v0 + v1 * v1 + v2 * v2 + v3 * v3;
      }
#pragma unroll
      for (int m = 1; m < 8; m <<= 1) { s += __shfl_xor(s, m, 64); ss += __shfl_xor(ss, m, 64); }
      const float mu = s * (1.f / 512.f);
      const float rs = rsqrtf(ss * (1.f / 512.f) - mu * mu + 1e-5f);
#pragma unroll
      for (int j = 0; j < 16; ++j) {
        const int jj = kk8 + 8 * j;
        const f32x4 sc4 = *(const f32x4*)(lnSl + 4 * jj);
        const f32x4 bi4 = *(const f32x4*)(lnBl + 4 * jj);
        const unsigned lo = (unsigned)xr[j], hi = (unsigned)(xr[j] >> 32);
        const float a0 = (bflo(lo) - mu) * rs * sc4[0] + bi4[0];
        const float a1 = (bfhi(lo) - mu) * rs * sc4[1] + bi4[1];
        const float a2 = (bflo(hi) - mu) * rs * sc4[2] + bi4[2];
        const float a3 = (bfhi(hi) - mu) * rs * sc4[3] + bi4[3];
        *(unsigned long long*)(xarea + ((rr * 1024 + jj * 8) ^ ((rr & 7) << 4))) =
            (unsigned long long)pack2bf(a0, a1) | ((unsigned long long)pack2bf(a2, a3) << 32);
      }
    }

    __syncthreads();   // (5) xarea ready; gacc reads done before next write
  }
}

// ---------------- fused final LayerNorm + output head ----------------
__global__ __launch_bounds__(256) void k_lnout(const unsigned* __restrict__ Rin,
                                               const float* __restrict__ lnS,
                                               const float* __restrict__ lnB,
                                               const float* __restrict__ ow,
                                               const float* __restrict__ ob,
                                               float* __restrict__ y) {
  int row  = blockIdx.x * 4 + (threadIdx.x >> 6);
  int lane = threadIdx.x & 63;
  const i32x4 v = *(const i32x4*)(Rin + (size_t)row * 256 + lane * 4);
  float xv[8];
#pragma unroll
  for (int j = 0; j < 4; ++j) {
    unsigned u = (unsigned)v[j];
    xv[2*j]   = bflo(u);
    xv[2*j+1] = bfhi(u);
  }
  float s = 0.f, s2 = 0.f;
#pragma unroll
  for (int j = 0; j < 8; ++j) { s += xv[j]; s2 += xv[j] * xv[j]; }
#pragma unroll
  for (int m = 1; m < 64; m <<= 1) { s += __shfl_xor(s, m, 64); s2 += __shfl_xor(s2, m, 64); }
  float mu  = s * (1.f / 512.f);
  float var = s2 * (1.f / 512.f) - mu * mu;
  float rs  = rsqrtf(var + 1e-5f);
  const float* Sp = lnS + 5 * 512 + lane * 8;
  const float* Bp = lnB + 5 * 512 + lane * 8;
  const float* wp = ow + lane * 8;
  float acc = 0.f;
#pragma unroll
  for (int j = 0; j < 8; ++j)
    acc += ((xv[j] - mu) * rs * Sp[j] + Bp[j]) * wp[j];
#pragma unroll
  for (int m = 1; m < 64; m <<= 1) acc += __shfl_xor(acc, m, 64);
  if (lane == 0) y[row] = acc + ob[0];
}

extern "C" void kernel_launch(void* const* d_in, const int* in_sizes, int n_in,
                              void* d_out, int out_size, void* d_ws, size_t ws_size,
                              hipStream_t stream) {
  (void)in_sizes; (void)n_in; (void)out_size; (void)ws_size;
  const float* x   = (const float*)d_in[0];
  const float* ipw = (const float*)d_in[1];
  const float* ipb = (const float*)d_in[2];
  const float* Wih = (const float*)d_in[3];
  const float* Whh = (const float*)d_in[4];
  const float* bih = (const float*)d_in[5];
  const float* bhh = (const float*)d_in[6];
  const float* lnS = (const float*)d_in[7];
  const float* lnB = (const float*)d_in[8];
  const float* ow  = (const float*)d_in[9];
  const float* ob  = (const float*)d_in[10];
  float* y = (float*)d_out;

  char* ws = (char*)d_ws;
  unsigned* Flg             = (unsigned*)ws;                         // 768 B packed
  unsigned* Prog            = (unsigned*)(ws + 1024);                // 768 B packed
  float* XP                 = (float*)(ws + 32768);                  // 64 KB
  float* XG0                = (float*)(ws + 98304);                  // 256 KB
  unsigned long long* Hst   = (unsigned long long*)(ws + 360448);    // 384 KB
  unsigned long long* Roll  = (unsigned long long*)(ws + 753664);    // 640 KB
  unsigned* RB              = (unsigned*)(ws + 2097152);             // 67.1 MB

  hipMemsetAsync(ws, 0, 4096, stream);        // Flg + Prog
  k_inproj<<<64, 256, 0, stream>>>(x, ipw, ipb, XP);
  k_xg0<<<256, 256, 0, stream>>>(XP, Wih, bih, XG0);
  k_pipe<<<192, 256, 0, stream>>>(Wih, Whh, bih, bhh, lnS, lnB, XG0, XP,
                                  Hst, Roll, RB, Flg, Prog);
  k_lnout<<<16384, 256, 0, stream>>>(RB, lnS, lnB, ow, ob, y);
}